// Round 5
// baseline (11911.455 us; speedup 1.0000x reference)
//
#include <hip/hip_runtime.h>
#include <hip/hip_bf16.h>
#include <math.h>

// ---------------------------------------------------------------------------
// RAPMemory: LTC (liquid time-constant) scan + projection + Hopfield + belief
//
// Design:
//  - k_build : sparsify recurrent & sensory synapses into per-column CSC,
//              entries packed as float4 {A=sig*log2e, Bc=A*mu, Wm=softplus(w),
//              meta=idx|code<<12} (code: 1=+erev, 2=-erev, 0=zero erev).
//              Also precomputes softplus(gleak), gl*vleak, softplus(cm),
//              and ZEROES the vG exchange buffer + give-up flag (ws is
//              poisoned 0xAA each call; poison would falsely satisfy the
//              seq check).
//  - k_sens  : sensory gating depends only on inputs -> fully parallel
//              precompute of wns/wds for all (b,s).
//  - k_scan  : the sequential part. Grid 256 = 16 batches x 16 column-chunks.
//              Each WG holds its 32 columns' sparse weights in LDS (120 KB,
//              loaded once, reused 512*6 times). Per unfold, inter-WG exchange
//              via per-slot packed {seq32|val32} u64 relaxed agent atomics,
//              double-buffered (WAR-safe via the data-dependency chain:
//              spin-read -> LDS write -> barrier -> MAC -> dependent store; a
//              WG can only overwrite a buffer after observing seq values that
//              prove every reader consumed it). v double-buffered in LDS ->
//              ONE __syncthreads per unfold. 256 WGs x 124KB LDS -> exactly
//              1 WG/CU, co-resident. bid%8 XCD round-robin keeps a batch's 16
//              WGs on one XCD (exchange stays in one L2); agent scope keeps it
//              correct even if placement differs. BOUNDED spin + global
//              give-up flag: if co-residency ever fails, the kernel exits
//              with wrong results in <1s instead of hanging the harness.
//  - k_proj/k_kv/k_hop/k_belief : row-tiled fp32 GEMM-ish post kernels.
// ---------------------------------------------------------------------------

#define B_     16
#define S_     512
#define D_     576
#define U_     512
#define MOTOR_ 153
#define HID_   256
#define QTY_   32
// float4 slots per column. MUST be a multiple of 16 so the pad loop
// ((cnt+15)&~15 <= STRIDE) can never overflow into the next column.
// nnz ~ Binomial(576,0.3): mean 173, max over 512 cols ~ 212. 240 = +6 sigma.
#define STRIDE 240
#define LOG2E  1.4426950408889634f
#define SPIN_MAX (1 << 22)   // ~0.2-0.4 s; healthy wait is ~1-2 us

#if __has_builtin(__builtin_amdgcn_exp2f)
#define EXP2F(x) __builtin_amdgcn_exp2f(x)
#else
#define EXP2F(x) exp2f(x)
#endif
#if __has_builtin(__builtin_amdgcn_rcpf)
#define RCPF(x) __builtin_amdgcn_rcpf(x)
#else
#define RCPF(x) (1.0f/(x))
#endif
#if __has_builtin(__builtin_amdgcn_s_sleep)
#define SLEEP1() __builtin_amdgcn_s_sleep(1)
#else
#define SLEEP1()
#endif

// rcp with one Newton-Raphson step: ~0.5ulp, protects recurrent accumulation
__device__ __forceinline__ float rcp_nr(float x) {
  float r = RCPF(x);
  return r * (2.0f - x * r);
}

__device__ __forceinline__ float softplusf(float x) {
  return (x > 20.0f) ? x : log1pf(expf(x));
}

// ---------------------------------------------------------------------------
extern "C" __global__ __launch_bounds__(512)
void k_build(const float* __restrict__ smu, const float* __restrict__ ssig,
             const float* __restrict__ sw,  const float* __restrict__ smask,
             const float* __restrict__ serev,
             const float* __restrict__ rmu, const float* __restrict__ rsig,
             const float* __restrict__ rw,  const float* __restrict__ rmask,
             const float* __restrict__ rerev,
             const float* __restrict__ gleak, const float* __restrict__ vleak,
             const float* __restrict__ cm,
             float4* __restrict__ recW, float4* __restrict__ senW,
             int* __restrict__ recNit, int* __restrict__ senNit,
             float* __restrict__ glA, float* __restrict__ glvA,
             float* __restrict__ cmA, int* __restrict__ gflag,
             unsigned long long* __restrict__ vG)
{
  const int j = threadIdx.x;   // column (post-unit), 0..511
  if (blockIdx.x == 0) {
    float gl = softplusf(gleak[j]);
    glA[j] = gl; glvA[j] = gl * vleak[j];
    cmA[j] = softplusf(cm[j]);
    if (j == 0) gflag[0] = 0;
    // zero the exchange buffer: 2 bufs x 16 batches x 512 slots = 16384 u64
    #pragma unroll
    for (int t = 0; t < 32; ++t) vG[j + 512*t] = 0ull;
    int cnt = 0;
    for (int i = 0; i < U_; ++i) {
      float mk = rmask[i*U_ + j];
      if (mk != 0.0f) {
        float A  = rsig[i*U_ + j] * LOG2E;
        float Bc = A * rmu[i*U_ + j];
        float Wm = softplusf(rw[i*U_ + j]) * mk;
        float er = rerev[i*U_ + j];
        unsigned code = (er > 0.f) ? 1u : ((er < 0.f) ? 2u : 0u);
        if (cnt < STRIDE)
          recW[j*STRIDE + cnt] = make_float4(A, Bc, Wm,
                                 __uint_as_float((unsigned)i | (code << 12)));
        ++cnt;
      }
    }
    if (cnt > STRIDE) cnt = STRIDE;
    int padded = (cnt + 15) & ~15;        // <= STRIDE since STRIDE%16==0
    for (int t = cnt; t < padded; ++t)
      recW[j*STRIDE + t] = make_float4(0.f, 0.f, 0.f, __uint_as_float(0u));
    recNit[j] = padded >> 4;              // 16 parts/column in k_scan
  } else {
    int cnt = 0;
    for (int i = 0; i < D_; ++i) {
      float mk = smask[i*U_ + j];
      if (mk != 0.0f) {
        float A  = ssig[i*U_ + j] * LOG2E;
        float Bc = A * smu[i*U_ + j];
        float Wm = softplusf(sw[i*U_ + j]) * mk;
        float er = serev[i*U_ + j];
        unsigned code = (er > 0.f) ? 1u : ((er < 0.f) ? 2u : 0u);
        if (cnt < STRIDE)
          senW[j*STRIDE + cnt] = make_float4(A, Bc, Wm,
                                 __uint_as_float((unsigned)i | (code << 12)));
        ++cnt;
      }
    }
    if (cnt > STRIDE) cnt = STRIDE;
    int padded = (cnt + 15) & ~15;        // <= STRIDE
    for (int t = cnt; t < padded; ++t)
      senW[j*STRIDE + t] = make_float4(0.f, 0.f, 0.f, __uint_as_float(0u));
    senNit[j] = padded >> 3;              // 8 parts/column in k_sens
  }
}

// ---------------------------------------------------------------------------
extern "C" __global__ __launch_bounds__(256)
void k_sens(const float* __restrict__ x, const float* __restrict__ iw,
            const float* __restrict__ ib,
            const float4* __restrict__ senW, const int* __restrict__ senNit,
            float* __restrict__ sensN, float* __restrict__ sensD)
{
  __shared__ float4 wl[32*STRIDE];
  __shared__ float  itl[D_];
  const int chunk = blockIdx.x & 15;
  const int slice = blockIdx.x >> 4;      // 0..127, 64 (b,s) pairs each
  const int tid = threadIdx.x;
  for (int t = tid; t < 32*STRIDE; t += 256) wl[t] = senW[chunk*32*STRIDE + t];
  const int cl = tid >> 3, part = tid & 7;
  const int col = chunk*32 + cl;
  const int nIt = senNit[col];
  const int base = cl*STRIDE;
  __syncthreads();
  for (int pr = slice*64; pr < slice*64 + 64; ++pr) {
    for (int t = tid; t < D_; t += 256) itl[t] = x[pr*D_ + t]*iw[t] + ib[t];
    __syncthreads();
    float an = 0.f, ad = 0.f;
    for (int it = 0; it < nIt; ++it) {
      float4 w4 = wl[base + it*8 + part];
      unsigned meta = __float_as_uint(w4.w);
      float vv = itl[meta & 1023u];
      float e = EXP2F(w4.y - w4.x * vv);
      float r = rcp_nr(1.0f + e);
      ad += w4.z * r;
      unsigned code = meta >> 12;
      float we = (code == 1u) ? w4.z : ((code == 2u) ? -w4.z : 0.0f);
      an += we * r;
    }
    an += __shfl_xor(an, 1); an += __shfl_xor(an, 2); an += __shfl_xor(an, 4);
    ad += __shfl_xor(ad, 1); ad += __shfl_xor(ad, 2); ad += __shfl_xor(ad, 4);
    if (part == 0) { sensN[pr*U_ + col] = an; sensD[pr*U_ + col] = ad; }
    __syncthreads();
  }
}

// ---------------------------------------------------------------------------
extern "C" __global__ __launch_bounds__(512)
void k_scan(const float* __restrict__ ts,
            const float4* __restrict__ recW, const int* __restrict__ recNit,
            const float* __restrict__ glA, const float* __restrict__ glvA,
            const float* __restrict__ cmA,
            const float* __restrict__ sensN, const float* __restrict__ sensD,
            const float* __restrict__ ow, const float* __restrict__ ob,
            float* __restrict__ ltc, int* gflag, unsigned long long* vG,
            float* __restrict__ vT_out)
{
  __shared__ float4 wl[32*STRIDE];   // 120 KB
  __shared__ float  vl[2][U_];       // double-buffered state: 4 KB
  const int bid = blockIdx.x;
  const int batch = (bid & 7) + ((bid >> 7) << 3);  // XCD-local batches
  const int chunk = (bid >> 3) & 15;
  const int tid = threadIdx.x;
  for (int t = tid; t < 32*STRIDE; t += 512) wl[t] = recW[chunk*32*STRIDE + t];
  const int cl = tid >> 4, part = tid & 15;
  const int col = chunk*32 + cl;
  const int nIt = recNit[col];
  const int base = cl*STRIDE;
  float gl = 0.f, glv = 0.f, cmsp = 0.f;
  if (part == 0) { gl = glA[col]; glv = glvA[col]; cmsp = cmA[col]; }
  vl[0][tid] = 0.0f;
  // double-buffered exchange slots for this batch
  unsigned long long* vg0 = vG + batch*U_;
  unsigned long long* vg1 = vG + 16*U_ + batch*U_;
  // preload step 0 sensory terms (part==0 lanes only)
  float sn = 0.f, sd = 0.f, cmt = 0.f;
  if (part == 0) {
    float el = ts[batch*S_];
    sn = sensN[batch*S_*U_ + col];
    sd = sensD[batch*S_*U_ + col];
    cmt = cmsp / (el / 6.0f);            // exact reference operation order
  }
  __syncthreads();
  int p = 0, cur = 0;
  for (int s = 0; s < S_; ++s) {
    float snN = 0.f, sdN = 0.f, elN = 0.f;
    for (int u = 0; u < 6; ++u, ++p) {
      const float* vc = vl[cur];
      float wn = 0.f, wd = 0.f;
      for (int it = 0; it < nIt; ++it) {
        float4 w4 = wl[base + it*16 + part];
        unsigned meta = __float_as_uint(w4.w);
        float vv = vc[meta & 1023u];
        float e = EXP2F(w4.y - w4.x * vv);   // exp(sigma*(mu - v))
        float r = rcp_nr(1.0f + e);          // sigmoid(sigma*(v - mu))
        wd += w4.z * r;
        unsigned code = meta >> 12;
        float we = (code == 1u) ? w4.z : ((code == 2u) ? -w4.z : 0.0f);
        wn += we * r;
      }
      if (u == 0 && part == 0) {             // prefetch next step (5-unfold slack)
        int s2 = (s + 1 < S_) ? (s + 1) : (S_ - 1);
        elN = ts[batch*S_ + s2];
        snN = sensN[(batch*S_ + s2)*U_ + col];
        sdN = sensD[(batch*S_ + s2)*U_ + col];
      }
      wn += __shfl_xor(wn, 1); wd += __shfl_xor(wd, 1);
      wn += __shfl_xor(wn, 2); wd += __shfl_xor(wd, 2);
      wn += __shfl_xor(wn, 4); wd += __shfl_xor(wd, 4);
      wn += __shfl_xor(wn, 8); wd += __shfl_xor(wd, 8);
      unsigned long long* vg = (p & 1) ? vg1 : vg0;
      if (part == 0) {
        float vold = vc[col];
        float num = cmt*vold + glv + wn + sn;
        float den = cmt + gl + wd + sd + 1e-8f;
        float vnew = num / den;              // exact division for the state
        unsigned long long pk =
            ((unsigned long long)(unsigned)(p + 1) << 32) |
            (unsigned long long)__float_as_uint(vnew);
        __hip_atomic_store(&vg[col], pk, __ATOMIC_RELAXED,
                           __HIP_MEMORY_SCOPE_AGENT);
      }
      {
        // bounded spin: healthy exit in ~1-2us; on co-residency failure the
        // first waiter trips SPIN_MAX (~0.3s), sets gflag, everyone bails.
        const unsigned need = (unsigned)(p + 1);
        unsigned long long pk;
        int itc = 0;
        for (;;) {
          pk = __hip_atomic_load(&vg[tid], __ATOMIC_RELAXED,
                                 __HIP_MEMORY_SCOPE_AGENT);
          if ((unsigned)(pk >> 32) >= need) break;
          ++itc;
          if ((itc & 4095) == 0) {
            if (itc >= SPIN_MAX ||
                __hip_atomic_load(gflag, __ATOMIC_RELAXED,
                                  __HIP_MEMORY_SCOPE_AGENT) != 0) {
              __hip_atomic_store(gflag, 1, __ATOMIC_RELAXED,
                                 __HIP_MEMORY_SCOPE_AGENT);
              break;
            }
          }
          SLEEP1();
        }
        vl[cur ^ 1][tid] = __uint_as_float((unsigned)pk);
      }
      __syncthreads();   // vl[cur^1] fully written; vl[cur] reads all done
      cur ^= 1;
    }
    if (part == 0) {     // rotate prefetched sensory terms into place
      sn = snN; sd = sdN; cmt = cmsp / (elN / 6.0f);
    }
    if (chunk == 0) {
      for (int m = tid; m < MOTOR_; m += 512)
        ltc[(batch*S_ + s)*MOTOR_ + m] = vl[cur][m]*ow[m] + ob[m];
    }
  }
  if (chunk == 0) vT_out[batch*U_ + tid] = vl[cur][tid];
}

// ---------------------------------------------------------------------------
extern "C" __global__ __launch_bounds__(256)
void k_proj(const float* __restrict__ ltc, const float* __restrict__ pW,
            const float* __restrict__ pb, float* __restrict__ hbuf)
{
  __shared__ float lr[16*MOTOR_];
  const int rb = blockIdx.x * 16;
  const int tid = threadIdx.x;
  for (int t = tid; t < 16*MOTOR_; t += 256) lr[t] = ltc[rb*MOTOR_ + t];
  __syncthreads();
  float acc[16];
  #pragma unroll
  for (int r = 0; r < 16; ++r) acc[r] = 0.f;
  for (int i = 0; i < MOTOR_; ++i) {
    float wv = pW[i*HID_ + tid];
    #pragma unroll
    for (int r = 0; r < 16; ++r) acc[r] += lr[r*MOTOR_ + i] * wv;
  }
  float bb = pb[tid];
  #pragma unroll
  for (int r = 0; r < 16; ++r) hbuf[(rb + r)*HID_ + tid] = acc[r] + bb;
}

// ---------------------------------------------------------------------------
extern "C" __global__ __launch_bounds__(256)
void k_kv(const float* __restrict__ lookup, const float* __restrict__ targets,
          const float* __restrict__ Wk, const float* __restrict__ Wv,
          float* __restrict__ khvh)
{
  __shared__ float src[HID_];
  const int mat = blockIdx.x >> 5, pp = blockIdx.x & 31;
  const int tid = threadIdx.x;
  src[tid] = (mat ? targets : lookup)[pp*HID_ + tid];
  __syncthreads();
  const float* W = mat ? Wv : Wk;
  float a = 0.f;
  for (int i = 0; i < HID_; ++i) a += src[i] * W[i*HID_ + tid];
  khvh[mat*QTY_*HID_ + pp*HID_ + tid] = a;
}

// ---------------------------------------------------------------------------
extern "C" __global__ __launch_bounds__(256)
void k_hop(const float* __restrict__ hbuf, const float* __restrict__ Wq,
           const float* __restrict__ khvh, const float* __restrict__ Wo,
           const float* __restrict__ bo, float* __restrict__ outC)
{
  __shared__ float hr[16][HID_];
  __shared__ float qr[16][HID_];
  __shared__ float sc[QTY_][65];     // [proto][row*4+head], padded stride
  __shared__ float mr[16][HID_];
  const int rb = blockIdx.x * 16;
  const int tid = threadIdx.x;
  for (int t = tid; t < 16*HID_; t += 256) (&hr[0][0])[t] = hbuf[rb*HID_ + t];
  __syncthreads();
  {
    float acc[16];
    #pragma unroll
    for (int r = 0; r < 16; ++r) acc[r] = 0.f;
    for (int i = 0; i < HID_; ++i) {
      float wv = Wq[i*HID_ + tid];
      #pragma unroll
      for (int r = 0; r < 16; ++r) acc[r] += hr[r][i] * wv;
    }
    #pragma unroll
    for (int r = 0; r < 16; ++r) qr[r][tid] = acc[r];
  }
  __syncthreads();
  if (tid < 128) {                    // scores: 32 protos x 4 heads
    const int pp = tid >> 2, hh = tid & 3;
    const float* kp = khvh + pp*HID_ + hh*64;
    for (int row = 0; row < 16; ++row) {
      float sacc = 0.f;
      for (int d = 0; d < 64; ++d) sacc += qr[row][hh*64 + d] * kp[d];
      sc[pp][row*4 + hh] = sacc * 0.125f;   // 1/sqrt(64)
    }
  }
  __syncthreads();
  if (tid < 64) {                     // softmax over 32 protos
    const int c = tid;                // == row*4+head
    float mx = -1e30f;
    for (int pp = 0; pp < QTY_; ++pp) mx = fmaxf(mx, sc[pp][c]);
    float sum = 0.f;
    for (int pp = 0; pp < QTY_; ++pp) {
      float e = expf(sc[pp][c] - mx); sc[pp][c] = e; sum += e;
    }
    float inv = 1.f/sum;
    for (int pp = 0; pp < QTY_; ++pp) sc[pp][c] *= inv;
  }
  __syncthreads();
  {
    const int hh = tid >> 6;
    float acc[16];
    #pragma unroll
    for (int r = 0; r < 16; ++r) acc[r] = 0.f;
    for (int pp = 0; pp < QTY_; ++pp) {
      float vv = khvh[QTY_*HID_ + pp*HID_ + tid];
      #pragma unroll
      for (int r = 0; r < 16; ++r) acc[r] += sc[pp][r*4 + hh] * vv;
    }
    #pragma unroll
    for (int r = 0; r < 16; ++r) mr[r][tid] = acc[r];
  }
  __syncthreads();
  {
    float acc[16];
    #pragma unroll
    for (int r = 0; r < 16; ++r) acc[r] = 0.f;
    for (int i = 0; i < HID_; ++i) {
      float wv = Wo[i*HID_ + tid];
      #pragma unroll
      for (int r = 0; r < 16; ++r) acc[r] += mr[r][i] * wv;
    }
    float bb = bo[tid];
    #pragma unroll
    for (int r = 0; r < 16; ++r)
      outC[(rb + r)*HID_ + tid] = hr[r][tid] + acc[r] + bb;
  }
}

// ---------------------------------------------------------------------------
extern "C" __global__ __launch_bounds__(256)
void k_belief(const float* __restrict__ outC, const float* __restrict__ W1,
              const float* __restrict__ b1, const float* __restrict__ W2,
              const float* __restrict__ b2, float* __restrict__ outB)
{
  __shared__ float cr[16][HID_];
  __shared__ float trr[16][HID_];
  const int rb = blockIdx.x * 16;
  const int tid = threadIdx.x;
  for (int t = tid; t < 16*HID_; t += 256) (&cr[0][0])[t] = outC[rb*HID_ + t];
  __syncthreads();
  {
    float acc[16];
    #pragma unroll
    for (int r = 0; r < 16; ++r) acc[r] = 0.f;
    for (int i = 0; i < HID_; ++i) {
      float wv = W1[i*HID_ + tid];
      #pragma unroll
      for (int r = 0; r < 16; ++r) acc[r] += cr[r][i] * wv;
    }
    float bb = b1[tid];
    #pragma unroll
    for (int r = 0; r < 16; ++r) {
      float xx = acc[r] + bb;
      trr[r][tid] = xx / (1.0f + expf(-xx));   // silu (exact division)
    }
  }
  __syncthreads();
  {
    const int o = tid & 63, rr = tid >> 6;   // rr in 0..3
    float a4[4] = {0.f, 0.f, 0.f, 0.f};
    for (int i = 0; i < HID_; ++i) {
      float wv = W2[i*64 + o];
      a4[0] += trr[rr    ][i] * wv;
      a4[1] += trr[rr + 4][i] * wv;
      a4[2] += trr[rr + 8][i] * wv;
      a4[3] += trr[rr +12][i] * wv;
    }
    float bb = b2[o];
    outB[(rb + rr     )*64 + o] = a4[0] + bb;
    outB[(rb + rr + 4 )*64 + o] = a4[1] + bb;
    outB[(rb + rr + 8 )*64 + o] = a4[2] + bb;
    outB[(rb + rr + 12)*64 + o] = a4[3] + bb;
  }
}

// ---------------------------------------------------------------------------
extern "C" void kernel_launch(void* const* d_in, const int* in_sizes, int n_in,
                              void* d_out, int out_size, void* d_ws,
                              size_t ws_size, hipStream_t stream)
{
  const float* x       = (const float*)d_in[0];
  const float* ts      = (const float*)d_in[1];
  const float* iw      = (const float*)d_in[2];
  const float* ib      = (const float*)d_in[3];
  const float* ow      = (const float*)d_in[4];
  const float* ob      = (const float*)d_in[5];
  const float* smu     = (const float*)d_in[6];
  const float* ssig    = (const float*)d_in[7];
  const float* sw      = (const float*)d_in[8];
  const float* smask   = (const float*)d_in[9];
  const float* serev   = (const float*)d_in[10];
  const float* rmu     = (const float*)d_in[11];
  const float* rsig    = (const float*)d_in[12];
  const float* rw      = (const float*)d_in[13];
  const float* rmask   = (const float*)d_in[14];
  const float* rerev   = (const float*)d_in[15];
  const float* gleak   = (const float*)d_in[16];
  const float* vleak   = (const float*)d_in[17];
  const float* cm      = (const float*)d_in[18];
  const float* pW      = (const float*)d_in[19];
  const float* pb      = (const float*)d_in[20];
  const float* lookup  = (const float*)d_in[21];
  const float* targets = (const float*)d_in[22];
  const float* Wq      = (const float*)d_in[23];
  const float* Wk      = (const float*)d_in[24];
  const float* Wv      = (const float*)d_in[25];
  const float* Wo      = (const float*)d_in[26];
  const float* bo      = (const float*)d_in[27];
  const float* W1      = (const float*)d_in[28];
  const float* b1      = (const float*)d_in[29];
  const float* W2      = (const float*)d_in[30];
  const float* b2      = (const float*)d_in[31];

  // workspace layout (~49 MB)
  float4* recW  = (float4*)d_ws;                    // 512*240 float4
  float4* senW  = recW + 512*STRIDE;                // 512*240 float4
  int*    recNit = (int*)(senW + 512*STRIDE);       // 512
  int*    senNit = recNit + 512;                    // 512
  float*  glA   = (float*)(senNit + 512);           // 512
  float*  glvA  = glA + 512;                        // 512
  float*  cmA   = glvA + 512;                       // 512
  int*    gflag = (int*)(cmA + 512);                // 128 ints (512B, aligned)
  unsigned long long* vG = (unsigned long long*)(gflag + 128); // 2*16*512 u64
  float*  sensN = (float*)(vG + 2*16*U_);           // B*S*512
  float*  sensD = sensN + B_*S_*U_;                 // B*S*512
  float*  ltc   = sensD + B_*S_*U_;                 // B*S*153
  float*  hbuf  = ltc + B_*S_*MOTOR_;               // B*S*256
  float*  khvh  = hbuf + B_*S_*HID_;                // 2*32*256

  float* outC = (float*)d_out;                      // (B,S,256)
  float* outB = outC + B_*S_*HID_;                  // (B,S,64)
  float* outV = outB + B_*S_*64;                    // (B,512)

  k_build<<<dim3(2), dim3(512), 0, stream>>>(
      smu, ssig, sw, smask, serev, rmu, rsig, rw, rmask, rerev,
      gleak, vleak, cm, recW, senW, recNit, senNit, glA, glvA, cmA,
      gflag, vG);
  k_sens<<<dim3(2048), dim3(256), 0, stream>>>(
      x, iw, ib, senW, senNit, sensN, sensD);
  k_scan<<<dim3(256), dim3(512), 0, stream>>>(
      ts, recW, recNit, glA, glvA, cmA, sensN, sensD, ow, ob,
      ltc, gflag, vG, outV);
  k_proj<<<dim3(512), dim3(256), 0, stream>>>(ltc, pW, pb, hbuf);
  k_kv<<<dim3(64), dim3(256), 0, stream>>>(lookup, targets, Wk, Wv, khvh);
  k_hop<<<dim3(512), dim3(256), 0, stream>>>(hbuf, Wq, khvh, Wo, bo, outC);
  k_belief<<<dim3(512), dim3(256), 0, stream>>>(outC, W1, b1, W2, b2, outB);
}

// Round 8
// 11897.371 us; speedup vs baseline: 1.0012x; 1.0012x over previous
//
#include <hip/hip_runtime.h>
#include <hip/hip_bf16.h>
#include <math.h>

// ---------------------------------------------------------------------------
// RAPMemory: LTC (liquid time-constant) scan + projection + Hopfield + belief
//
// R5 counters: k_scan 9.99ms, VALUBusy 24.8%, FETCH 358MB, WRITE 201MB ->
// exchange congestion-bound (131K pollers + per-lane 8B stores = 64B-line
// write storm). R6/R7/R8: wave0-managed comm -- producers stage {seq|val} in
// LDS; wave0 issues ONE coalesced 256B store burst + polls all remote slots
// with 8 in-flight loads/lane (one ~900cyc round covers 480 slots). Motor &
// vT writes distributed across chunks (no straggler WG). R8 = R7 re-audited
// and resubmitted (R7 bench was an infra failure, never measured).
// Protocol (per-slot packed {seq32|val32} u64, double-buffered vG, agent
// scope): WAR-safe via the data-dependency chain spin-read -> LDS -> barrier
// -> MAC -> dependent store. Bounded spin + gflag => no-hang guarantee.
// ---------------------------------------------------------------------------

#define B_     16
#define S_     512
#define D_     576
#define U_     512
#define MOTOR_ 153
#define HID_   256
#define QTY_   32
// float4 slots per column; multiple of 16 so pad can't overflow (max nnz~212)
#define STRIDE 240
#define LOG2E  1.4426950408889634f
#define SPIN_ROUNDS (1 << 20)   // bounded no-hang; healthy poll: 1-3 rounds

#if __has_builtin(__builtin_amdgcn_exp2f)
#define EXP2F(x) __builtin_amdgcn_exp2f(x)
#else
#define EXP2F(x) exp2f(x)
#endif
#if __has_builtin(__builtin_amdgcn_rcpf)
#define RCPF(x) __builtin_amdgcn_rcpf(x)
#else
#define RCPF(x) (1.0f/(x))
#endif

__device__ __forceinline__ float rcp_nr(float x) {
  float r = RCPF(x);
  return r * (2.0f - x * r);
}

__device__ __forceinline__ float softplusf(float x) {
  return (x > 20.0f) ? x : log1pf(expf(x));
}

// ---------------------------------------------------------------------------
extern "C" __global__ __launch_bounds__(512)
void k_build(const float* __restrict__ smu, const float* __restrict__ ssig,
             const float* __restrict__ sw,  const float* __restrict__ smask,
             const float* __restrict__ serev,
             const float* __restrict__ rmu, const float* __restrict__ rsig,
             const float* __restrict__ rw,  const float* __restrict__ rmask,
             const float* __restrict__ rerev,
             const float* __restrict__ gleak, const float* __restrict__ vleak,
             const float* __restrict__ cm,
             float4* __restrict__ recW, float4* __restrict__ senW,
             int* __restrict__ recNit, int* __restrict__ senNit,
             float* __restrict__ glA, float* __restrict__ glvA,
             float* __restrict__ cmA, int* __restrict__ gflag,
             unsigned long long* __restrict__ vG)
{
  const int j = threadIdx.x;   // column (post-unit), 0..511
  if (blockIdx.x == 0) {
    float gl = softplusf(gleak[j]);
    glA[j] = gl; glvA[j] = gl * vleak[j];
    cmA[j] = softplusf(cm[j]);
    if (j == 0) gflag[0] = 0;
    // zero exchange buffer: 2 bufs x 16 batches x 512 slots (ws poison 0xAA
    // would falsely satisfy the seq>=need check)
    #pragma unroll
    for (int t = 0; t < 32; ++t) vG[j + 512*t] = 0ull;
    int cnt = 0;
    for (int i = 0; i < U_; ++i) {
      float mk = rmask[i*U_ + j];
      if (mk != 0.0f) {
        float A  = rsig[i*U_ + j] * LOG2E;
        float Bc = A * rmu[i*U_ + j];
        float Wm = softplusf(rw[i*U_ + j]) * mk;
        float er = rerev[i*U_ + j];
        unsigned code = (er > 0.f) ? 1u : ((er < 0.f) ? 2u : 0u);
        if (cnt < STRIDE)
          recW[j*STRIDE + cnt] = make_float4(A, Bc, Wm,
                                 __uint_as_float((unsigned)i | (code << 12)));
        ++cnt;
      }
    }
    if (cnt > STRIDE) cnt = STRIDE;
    int padded = (cnt + 15) & ~15;        // <= STRIDE since STRIDE%16==0
    for (int t = cnt; t < padded; ++t)
      recW[j*STRIDE + t] = make_float4(0.f, 0.f, 0.f, __uint_as_float(0u));
    recNit[j] = padded >> 4;              // 16 parts/column in k_scan
  } else {
    int cnt = 0;
    for (int i = 0; i < D_; ++i) {
      float mk = smask[i*U_ + j];
      if (mk != 0.0f) {
        float A  = ssig[i*U_ + j] * LOG2E;
        float Bc = A * smu[i*U_ + j];
        float Wm = softplusf(sw[i*U_ + j]) * mk;
        float er = serev[i*U_ + j];
        unsigned code = (er > 0.f) ? 1u : ((er < 0.f) ? 2u : 0u);
        if (cnt < STRIDE)
          senW[j*STRIDE + cnt] = make_float4(A, Bc, Wm,
                                 __uint_as_float((unsigned)i | (code << 12)));
        ++cnt;
      }
    }
    if (cnt > STRIDE) cnt = STRIDE;
    int padded = (cnt + 15) & ~15;        // <= STRIDE
    for (int t = cnt; t < padded; ++t)
      senW[j*STRIDE + t] = make_float4(0.f, 0.f, 0.f, __uint_as_float(0u));
    senNit[j] = padded >> 3;              // 8 parts/column in k_sens
  }
}

// ---------------------------------------------------------------------------
extern "C" __global__ __launch_bounds__(256)
void k_sens(const float* __restrict__ x, const float* __restrict__ iw,
            const float* __restrict__ ib,
            const float4* __restrict__ senW, const int* __restrict__ senNit,
            float* __restrict__ sensN, float* __restrict__ sensD)
{
  __shared__ float4 wl[32*STRIDE];
  __shared__ float  itl[D_];
  const int chunk = blockIdx.x >> 6;      // 0..15; 64 consecutive bids share
  const int slice = blockIdx.x & 63;      // a weight chunk (L2-friendly)
  const int tid = threadIdx.x;
  for (int t = tid; t < 32*STRIDE; t += 256) wl[t] = senW[chunk*32*STRIDE + t];
  const int cl = tid >> 3, part = tid & 7;
  const int col = chunk*32 + cl;
  const int nIt = senNit[col];
  const int base = cl*STRIDE;
  __syncthreads();
  for (int pr = slice*128; pr < slice*128 + 128; ++pr) {   // 128 (b,s)/block
    for (int t = tid; t < D_; t += 256) itl[t] = x[pr*D_ + t]*iw[t] + ib[t];
    __syncthreads();
    float an = 0.f, ad = 0.f;
    for (int it = 0; it < nIt; ++it) {
      float4 w4 = wl[base + it*8 + part];
      unsigned meta = __float_as_uint(w4.w);
      float vv = itl[meta & 1023u];
      float e = EXP2F(w4.y - w4.x * vv);
      float r = rcp_nr(1.0f + e);
      ad += w4.z * r;
      unsigned code = meta >> 12;
      float we = (code == 1u) ? w4.z : ((code == 2u) ? -w4.z : 0.0f);
      an += we * r;
    }
    an += __shfl_xor(an, 1); an += __shfl_xor(an, 2); an += __shfl_xor(an, 4);
    ad += __shfl_xor(ad, 1); ad += __shfl_xor(ad, 2); ad += __shfl_xor(ad, 4);
    if (part == 0) { sensN[pr*U_ + col] = an; sensD[pr*U_ + col] = ad; }
    __syncthreads();
  }
}

// ---------------------------------------------------------------------------
extern "C" __global__ __launch_bounds__(512)
void k_scan(const float* __restrict__ ts,
            const float4* __restrict__ recW, const int* __restrict__ recNit,
            const float* __restrict__ glA, const float* __restrict__ glvA,
            const float* __restrict__ cmA,
            const float* __restrict__ sensN, const float* __restrict__ sensD,
            const float* __restrict__ ow, const float* __restrict__ ob,
            float* __restrict__ ltc, int* gflag, unsigned long long* vG,
            float* __restrict__ vT_out)
{
  __shared__ float4 wl[32*STRIDE];            // 120 KB
  __shared__ float  vl[2][U_];                // double-buffered state: 4 KB
  __shared__ unsigned long long pkStage[32];  // producer staging: 256 B
  const int bid = blockIdx.x;
  const int batch = (bid & 7) + ((bid >> 7) << 3);  // XCD-local batches
  const int chunk = (bid >> 3) & 15;
  const int tid = threadIdx.x;
  for (int t = tid; t < 32*STRIDE; t += 512) wl[t] = recW[chunk*32*STRIDE + t];
  const int cl = tid >> 4, part = tid & 15;
  const int col = chunk*32 + cl;
  const int nIt = recNit[col];
  const int base = cl*STRIDE;
  const int wave = tid >> 6, lane = tid & 63;
  // wave0 poll assignment: lane i owns slots [8i, 8i+8); lanes 4c..4c+3 are
  // this WG's own chunk (values come from LDS, never polled)
  const bool ownLane = (lane >= 4*chunk) && (lane < 4*chunk + 4);
  // distributed motor write: this chunk owns cols [32c, 32c+32) of ltc
  const int mcol = chunk*32 + (tid & 31);
  const bool mWrite = (tid < 32) && (mcol < MOTOR_);
  float mow = 0.f, mob = 0.f;
  if (mWrite) { mow = ow[mcol]; mob = ob[mcol]; }
  float gl = 0.f, glv = 0.f, cmsp = 0.f;
  if (part == 0) { gl = glA[col]; glv = glvA[col]; cmsp = cmA[col]; }
  vl[0][tid] = 0.0f;
  unsigned long long* vg0 = vG + batch*U_;
  unsigned long long* vg1 = vG + 16*U_ + batch*U_;
  float sn = 0.f, sd = 0.f, cmt = 0.f;
  if (part == 0) {
    float el = ts[batch*S_];
    sn = sensN[batch*S_*U_ + col];
    sd = sensD[batch*S_*U_ + col];
    cmt = cmsp / (el / 6.0f);            // exact reference operation order
  }
  __syncthreads();
  int p = 0, cur = 0;
  for (int s = 0; s < S_; ++s) {
    float snN = 0.f, sdN = 0.f, elN = 0.f;
    for (int u = 0; u < 6; ++u, ++p) {
      const float* vc = vl[cur];
      float* vlN = vl[cur ^ 1];
      float wn = 0.f, wd = 0.f;
      for (int it = 0; it < nIt; ++it) {
        float4 w4 = wl[base + it*16 + part];
        unsigned meta = __float_as_uint(w4.w);
        float vv = vc[meta & 1023u];
        float e = EXP2F(w4.y - w4.x * vv);   // exp(sigma*(mu - v))
        float r = rcp_nr(1.0f + e);          // sigmoid(sigma*(v - mu))
        wd += w4.z * r;
        unsigned code = meta >> 12;
        float we = (code == 1u) ? w4.z : ((code == 2u) ? -w4.z : 0.0f);
        wn += we * r;
      }
      if (u == 0 && part == 0) {             // prefetch next step (5-unfold slack)
        int s2 = (s + 1 < S_) ? (s + 1) : (S_ - 1);
        elN = ts[batch*S_ + s2];
        snN = sensN[(batch*S_ + s2)*U_ + col];
        sdN = sensD[(batch*S_ + s2)*U_ + col];
      }
      wn += __shfl_xor(wn, 1); wd += __shfl_xor(wd, 1);
      wn += __shfl_xor(wn, 2); wd += __shfl_xor(wd, 2);
      wn += __shfl_xor(wn, 4); wd += __shfl_xor(wd, 4);
      wn += __shfl_xor(wn, 8); wd += __shfl_xor(wd, 8);
      unsigned long long* vg = (p & 1) ? vg1 : vg0;
      const unsigned need = (unsigned)(p + 1);
      if (part == 0) {
        float vold = vc[col];
        float num = cmt*vold + glv + wn + sn;
        float den = cmt + gl + wd + sd + 1e-8f;
        float vnew = num / den;              // exact division for the state
        vlN[col] = vnew;                     // own values: LDS direct
        pkStage[cl] = ((unsigned long long)need << 32) |
                      (unsigned long long)__float_as_uint(vnew);
      }
      __syncthreads();   // A: pkStage+vlN[own] ready; all reads of vc done
      if (wave == 0) {
        if (lane < 32) {                     // ONE coalesced 256B burst
          __hip_atomic_store(&vg[chunk*32 + lane], pkStage[lane],
                             __ATOMIC_RELAXED, __HIP_MEMORY_SCOPE_AGENT);
        }
        unsigned pend = ownLane ? 0u : 0xFFu;
        int rounds = 0;
        while (pend) {
          unsigned long long t[8];
          #pragma unroll
          for (int j = 0; j < 8; ++j)
            if (pend & (1u << j))
              t[j] = __hip_atomic_load(&vg[8*lane + j], __ATOMIC_RELAXED,
                                       __HIP_MEMORY_SCOPE_AGENT);
          #pragma unroll
          for (int j = 0; j < 8; ++j)
            if ((pend & (1u << j)) && (unsigned)(t[j] >> 32) >= need) {
              vlN[8*lane + j] = __uint_as_float((unsigned)t[j]);
              pend &= ~(1u << j);
            }
          if ((++rounds & 63) == 0) {        // bounded: no-hang guarantee
            if (rounds >= SPIN_ROUNDS ||
                __hip_atomic_load(gflag, __ATOMIC_RELAXED,
                                  __HIP_MEMORY_SCOPE_AGENT) != 0) {
              __hip_atomic_store(gflag, 1, __ATOMIC_RELAXED,
                                 __HIP_MEMORY_SCOPE_AGENT);
              break;
            }
          }
        }
      }
      __syncthreads();   // B: vlN complete
      cur ^= 1;
    }
    if (part == 0) {     // rotate prefetched sensory terms into place
      sn = snN; sd = sdN; cmt = cmsp / (elN / 6.0f);
    }
    // distributed motor-slice write: 32 lanes/WG, hidden under next MAC
    if (mWrite)
      ltc[(batch*S_ + s)*MOTOR_ + mcol] = vl[cur][mcol]*mow + mob;
  }
  // distributed final-state write: each chunk stores its own 32 columns
  if (tid < 32)
    vT_out[batch*U_ + chunk*32 + tid] = vl[cur][chunk*32 + tid];
}

// ---------------------------------------------------------------------------
extern "C" __global__ __launch_bounds__(256)
void k_proj(const float* __restrict__ ltc, const float* __restrict__ pW,
            const float* __restrict__ pb, float* __restrict__ hbuf)
{
  __shared__ float lr[16*MOTOR_];
  const int rb = blockIdx.x * 16;
  const int tid = threadIdx.x;
  for (int t = tid; t < 16*MOTOR_; t += 256) lr[t] = ltc[rb*MOTOR_ + t];
  __syncthreads();
  float acc[16];
  #pragma unroll
  for (int r = 0; r < 16; ++r) acc[r] = 0.f;
  for (int i = 0; i < MOTOR_; ++i) {
    float wv = pW[i*HID_ + tid];
    #pragma unroll
    for (int r = 0; r < 16; ++r) acc[r] += lr[r*MOTOR_ + i] * wv;
  }
  float bb = pb[tid];
  #pragma unroll
  for (int r = 0; r < 16; ++r) hbuf[(rb + r)*HID_ + tid] = acc[r] + bb;
}

// ---------------------------------------------------------------------------
extern "C" __global__ __launch_bounds__(256)
void k_kv(const float* __restrict__ lookup, const float* __restrict__ targets,
          const float* __restrict__ Wk, const float* __restrict__ Wv,
          float* __restrict__ khvh)
{
  __shared__ float src[HID_];
  const int mat = blockIdx.x >> 5, pp = blockIdx.x & 31;
  const int tid = threadIdx.x;
  src[tid] = (mat ? targets : lookup)[pp*HID_ + tid];
  __syncthreads();
  const float* W = mat ? Wv : Wk;
  float a = 0.f;
  for (int i = 0; i < HID_; ++i) a += src[i] * W[i*HID_ + tid];
  khvh[mat*QTY_*HID_ + pp*HID_ + tid] = a;
}

// ---------------------------------------------------------------------------
extern "C" __global__ __launch_bounds__(256)
void k_hop(const float* __restrict__ hbuf, const float* __restrict__ Wq,
           const float* __restrict__ khvh, const float* __restrict__ Wo,
           const float* __restrict__ bo, float* __restrict__ outC)
{
  __shared__ float hr[16][HID_];
  __shared__ float qr[16][HID_];
  __shared__ float sc[QTY_][65];     // [proto][row*4+head], padded stride
  __shared__ float mr[16][HID_];
  const int rb = blockIdx.x * 16;
  const int tid = threadIdx.x;
  for (int t = tid; t < 16*HID_; t += 256) (&hr[0][0])[t] = hbuf[rb*HID_ + t];
  __syncthreads();
  {
    float acc[16];
    #pragma unroll
    for (int r = 0; r < 16; ++r) acc[r] = 0.f;
    for (int i = 0; i < HID_; ++i) {
      float wv = Wq[i*HID_ + tid];
      #pragma unroll
      for (int r = 0; r < 16; ++r) acc[r] += hr[r][i] * wv;
    }
    #pragma unroll
    for (int r = 0; r < 16; ++r) qr[r][tid] = acc[r];
  }
  __syncthreads();
  if (tid < 128) {                    // scores: 32 protos x 4 heads
    const int pp = tid >> 2, hh = tid & 3;
    const float* kp = khvh + pp*HID_ + hh*64;
    for (int row = 0; row < 16; ++row) {
      float sacc = 0.f;
      for (int d = 0; d < 64; ++d) sacc += qr[row][hh*64 + d] * kp[d];
      sc[pp][row*4 + hh] = sacc * 0.125f;   // 1/sqrt(64)
    }
  }
  __syncthreads();
  if (tid < 64) {                     // softmax over 32 protos
    const int c = tid;                // == row*4+head
    float mx = -1e30f;
    for (int pp = 0; pp < QTY_; ++pp) mx = fmaxf(mx, sc[pp][c]);
    float sum = 0.f;
    for (int pp = 0; pp < QTY_; ++pp) {
      float e = expf(sc[pp][c] - mx); sc[pp][c] = e; sum += e;
    }
    float inv = 1.f/sum;
    for (int pp = 0; pp < QTY_; ++pp) sc[pp][c] *= inv;
  }
  __syncthreads();
  {
    const int hh = tid >> 6;
    float acc[16];
    #pragma unroll
    for (int r = 0; r < 16; ++r) acc[r] = 0.f;
    for (int pp = 0; pp < QTY_; ++pp) {
      float vv = khvh[QTY_*HID_ + pp*HID_ + tid];
      #pragma unroll
      for (int r = 0; r < 16; ++r) acc[r] += sc[pp][r*4 + hh] * vv;
    }
    #pragma unroll
    for (int r = 0; r < 16; ++r) mr[r][tid] = acc[r];
  }
  __syncthreads();
  {
    float acc[16];
    #pragma unroll
    for (int r = 0; r < 16; ++r) acc[r] = 0.f;
    for (int i = 0; i < HID_; ++i) {
      float wv = Wo[i*HID_ + tid];
      #pragma unroll
      for (int r = 0; r < 16; ++r) acc[r] += mr[r][i] * wv;
    }
    float bb = bo[tid];
    #pragma unroll
    for (int r = 0; r < 16; ++r)
      outC[(rb + r)*HID_ + tid] = hr[r][tid] + acc[r] + bb;
  }
}

// ---------------------------------------------------------------------------
extern "C" __global__ __launch_bounds__(256)
void k_belief(const float* __restrict__ outC, const float* __restrict__ W1,
              const float* __restrict__ b1, const float* __restrict__ W2,
              const float* __restrict__ b2, float* __restrict__ outB)
{
  __shared__ float cr[16][HID_];
  __shared__ float trr[16][HID_];
  const int rb = blockIdx.x * 16;
  const int tid = threadIdx.x;
  for (int t = tid; t < 16*HID_; t += 256) (&cr[0][0])[t] = outC[rb*HID_ + t];
  __syncthreads();
  {
    float acc[16];
    #pragma unroll
    for (int r = 0; r < 16; ++r) acc[r] = 0.f;
    for (int i = 0; i < HID_; ++i) {
      float wv = W1[i*HID_ + tid];
      #pragma unroll
      for (int r = 0; r < 16; ++r) acc[r] += cr[r][i] * wv;
    }
    float bb = b1[tid];
    #pragma unroll
    for (int r = 0; r < 16; ++r) {
      float xx = acc[r] + bb;
      trr[r][tid] = xx / (1.0f + expf(-xx));   // silu (exact division)
    }
  }
  __syncthreads();
  {
    const int o = tid & 63, rr = tid >> 6;   // rr in 0..3
    float a4[4] = {0.f, 0.f, 0.f, 0.f};
    for (int i = 0; i < HID_; ++i) {
      float wv = W2[i*64 + o];
      a4[0] += trr[rr    ][i] * wv;
      a4[1] += trr[rr + 4][i] * wv;
      a4[2] += trr[rr + 8][i] * wv;
      a4[3] += trr[rr +12][i] * wv;
    }
    float bb = b2[o];
    outB[(rb + rr     )*64 + o] = a4[0] + bb;
    outB[(rb + rr + 4 )*64 + o] = a4[1] + bb;
    outB[(rb + rr + 8 )*64 + o] = a4[2] + bb;
    outB[(rb + rr + 12)*64 + o] = a4[3] + bb;
  }
}

// ---------------------------------------------------------------------------
extern "C" void kernel_launch(void* const* d_in, const int* in_sizes, int n_in,
                              void* d_out, int out_size, void* d_ws,
                              size_t ws_size, hipStream_t stream)
{
  const float* x       = (const float*)d_in[0];
  const float* ts      = (const float*)d_in[1];
  const float* iw      = (const float*)d_in[2];
  const float* ib      = (const float*)d_in[3];
  const float* ow      = (const float*)d_in[4];
  const float* ob      = (const float*)d_in[5];
  const float* smu     = (const float*)d_in[6];
  const float* ssig    = (const float*)d_in[7];
  const float* sw      = (const float*)d_in[8];
  const float* smask   = (const float*)d_in[9];
  const float* serev   = (const float*)d_in[10];
  const float* rmu     = (const float*)d_in[11];
  const float* rsig    = (const float*)d_in[12];
  const float* rw      = (const float*)d_in[13];
  const float* rmask   = (const float*)d_in[14];
  const float* rerev   = (const float*)d_in[15];
  const float* gleak   = (const float*)d_in[16];
  const float* vleak   = (const float*)d_in[17];
  const float* cm      = (const float*)d_in[18];
  const float* pW      = (const float*)d_in[19];
  const float* pb      = (const float*)d_in[20];
  const float* lookup  = (const float*)d_in[21];
  const float* targets = (const float*)d_in[22];
  const float* Wq      = (const float*)d_in[23];
  const float* Wk      = (const float*)d_in[24];
  const float* Wv      = (const float*)d_in[25];
  const float* Wo      = (const float*)d_in[26];
  const float* bo      = (const float*)d_in[27];
  const float* W1      = (const float*)d_in[28];
  const float* b1      = (const float*)d_in[29];
  const float* W2      = (const float*)d_in[30];
  const float* b2      = (const float*)d_in[31];

  // workspace layout (~49 MB)
  float4* recW  = (float4*)d_ws;                    // 512*240 float4
  float4* senW  = recW + 512*STRIDE;                // 512*240 float4
  int*    recNit = (int*)(senW + 512*STRIDE);       // 512
  int*    senNit = recNit + 512;                    // 512
  float*  glA   = (float*)(senNit + 512);           // 512
  float*  glvA  = glA + 512;                        // 512
  float*  cmA   = glvA + 512;                       // 512
  int*    gflag = (int*)(cmA + 512);                // 128 ints (512B, aligned)
  unsigned long long* vG = (unsigned long long*)(gflag + 128); // 2*16*512 u64
  float*  sensN = (float*)(vG + 2*16*U_);           // B*S*512
  float*  sensD = sensN + B_*S_*U_;                 // B*S*512
  float*  ltc   = sensD + B_*S_*U_;                 // B*S*153
  float*  hbuf  = ltc + B_*S_*MOTOR_;               // B*S*256
  float*  khvh  = hbuf + B_*S_*HID_;                // 2*32*256

  float* outC = (float*)d_out;                      // (B,S,256)
  float* outB = outC + B_*S_*HID_;                  // (B,S,64)
  float* outV = outB + B_*S_*64;                    // (B,512)

  k_build<<<dim3(2), dim3(512), 0, stream>>>(
      smu, ssig, sw, smask, serev, rmu, rsig, rw, rmask, rerev,
      gleak, vleak, cm, recW, senW, recNit, senNit, glA, glvA, cmA,
      gflag, vG);
  k_sens<<<dim3(1024), dim3(256), 0, stream>>>(
      x, iw, ib, senW, senNit, sensN, sensD);
  k_scan<<<dim3(256), dim3(512), 0, stream>>>(
      ts, recW, recNit, glA, glvA, cmA, sensN, sensD, ow, ob,
      ltc, gflag, vG, outV);
  k_proj<<<dim3(512), dim3(256), 0, stream>>>(ltc, pW, pb, hbuf);
  k_kv<<<dim3(64), dim3(256), 0, stream>>>(lookup, targets, Wk, Wv, khvh);
  k_hop<<<dim3(512), dim3(256), 0, stream>>>(hbuf, Wq, khvh, Wo, bo, outC);
  k_belief<<<dim3(512), dim3(256), 0, stream>>>(outC, W1, b1, W2, b2, outB);
}